// Round 1
// baseline (247.487 us; speedup 1.0000x reference)
//
#include <hip/hip_runtime.h>

// FuzzySystemLayer: B=262144 rows, C=256 clusters, D=64 dims, O=8 outputs (all fp32)
// out[b,o] = sum_c memb[b,c] * W[c,o] / sum_c memb[b,c]
// memb[b,c] = exp(-(||x_b||^2 + ||c_c||^2 - 2 x_b.c_c) / (2 w_c^2))

#define NB 262144
#define NC 256
#define ND 64
#define NO 8
#define PK_STRIDE 80  // floats per cluster in packed workspace (320 B, 16B-aligned)

// packed[c][ 0..63] = center row
// packed[c][64]     = A  = 2*k          (k = log2(e) / (2 w^2))
// packed[c][65]     = k
// packed[c][66]     = Bc = c_sq * k
// packed[c][67..74] = W[c][0..7]
// packed[c][75..79] = pad

__global__ void fuzzy_prep(const float* __restrict__ centers,
                           const float* __restrict__ widths,
                           const float* __restrict__ W,
                           float* __restrict__ packed) {
    const int c = blockIdx.x;   // 256 blocks
    const int d = threadIdx.x;  // 64 threads = 1 wave
    float v = centers[c * ND + d];
    float sq = v * v;
    // wave(64)-wide reduction
    for (int off = 32; off > 0; off >>= 1)
        sq += __shfl_down(sq, off);
    float c_sq = __shfl(sq, 0);

    float* pk = packed + c * PK_STRIDE;
    pk[d] = v;
    if (d == 0) {
        const float LOG2E = 1.4426950408889634f;
        float w = widths[c];
        float k = LOG2E / (2.0f * w * w);
        pk[64] = 2.0f * k;
        pk[65] = k;
        pk[66] = c_sq * k;
    }
    if (d < NO) pk[67 + d] = W[c * NO + d];
    if (d >= NO && d < 13) pk[67 + d] = 0.0f;  // pad deterministic
}

__global__ __launch_bounds__(256) void fuzzy_main(
    const float* __restrict__ x,
    const float* __restrict__ packed,
    float* __restrict__ out) {
    const int b = blockIdx.x * blockDim.x + threadIdx.x;

    // Load this row's 64 floats into registers (16 x float4)
    const float4* xp = reinterpret_cast<const float4*>(x + (size_t)b * ND);
    float4 xv[16];
#pragma unroll
    for (int i = 0; i < 16; ++i) xv[i] = xp[i];

    float x_sq = 0.0f;
#pragma unroll
    for (int i = 0; i < 16; ++i) {
        x_sq = fmaf(xv[i].x, xv[i].x, x_sq);
        x_sq = fmaf(xv[i].y, xv[i].y, x_sq);
        x_sq = fmaf(xv[i].z, xv[i].z, x_sq);
        x_sq = fmaf(xv[i].w, xv[i].w, x_sq);
    }

    float sum = 0.0f;
    float acc[NO];
#pragma unroll
    for (int o = 0; o < NO; ++o) acc[o] = 0.0f;

    for (int c = 0; c < NC; ++c) {
        const float* pk = packed + c * PK_STRIDE;  // wave-uniform address -> s_load
        const float4* cv = reinterpret_cast<const float4*>(pk);
        float d0 = 0.f, d1 = 0.f, d2 = 0.f, d3 = 0.f;
#pragma unroll
        for (int i = 0; i < 16; i += 4) {
            float4 c0 = cv[i + 0], c1 = cv[i + 1], c2 = cv[i + 2], c3 = cv[i + 3];
            d0 = fmaf(xv[i + 0].x, c0.x, d0);
            d0 = fmaf(xv[i + 0].y, c0.y, d0);
            d0 = fmaf(xv[i + 0].z, c0.z, d0);
            d0 = fmaf(xv[i + 0].w, c0.w, d0);
            d1 = fmaf(xv[i + 1].x, c1.x, d1);
            d1 = fmaf(xv[i + 1].y, c1.y, d1);
            d1 = fmaf(xv[i + 1].z, c1.z, d1);
            d1 = fmaf(xv[i + 1].w, c1.w, d1);
            d2 = fmaf(xv[i + 2].x, c2.x, d2);
            d2 = fmaf(xv[i + 2].y, c2.y, d2);
            d2 = fmaf(xv[i + 2].z, c2.z, d2);
            d2 = fmaf(xv[i + 2].w, c2.w, d2);
            d3 = fmaf(xv[i + 3].x, c3.x, d3);
            d3 = fmaf(xv[i + 3].y, c3.y, d3);
            d3 = fmaf(xv[i + 3].z, c3.z, d3);
            d3 = fmaf(xv[i + 3].w, c3.w, d3);
        }
        float dot = (d0 + d1) + (d2 + d3);

        float A  = pk[64];
        float k  = pk[65];
        float Bc = pk[66];
        // exp2((2*dot - x_sq - c_sq) * k)
        float e2 = fmaf(dot, A, -fmaf(x_sq, k, Bc));
        float m = __builtin_amdgcn_exp2f(e2);
        sum += m;
#pragma unroll
        for (int o = 0; o < NO; ++o)
            acc[o] = fmaf(m, pk[67 + o], acc[o]);
    }

    float inv = 1.0f / sum;
    float4 o0, o1;
    o0.x = acc[0] * inv; o0.y = acc[1] * inv; o0.z = acc[2] * inv; o0.w = acc[3] * inv;
    o1.x = acc[4] * inv; o1.y = acc[5] * inv; o1.z = acc[6] * inv; o1.w = acc[7] * inv;
    float4* op = reinterpret_cast<float4*>(out + (size_t)b * NO);
    op[0] = o0;
    op[1] = o1;
}

extern "C" void kernel_launch(void* const* d_in, const int* in_sizes, int n_in,
                              void* d_out, int out_size, void* d_ws, size_t ws_size,
                              hipStream_t stream) {
    const float* x       = (const float*)d_in[0];  // [B, D]
    const float* centers = (const float*)d_in[1];  // [C, D]
    const float* widths  = (const float*)d_in[2];  // [C]
    const float* W       = (const float*)d_in[3];  // [C, O]
    float* out = (float*)d_out;                     // [B, O]
    float* packed = (float*)d_ws;                   // needs 256*80*4 = 80 KiB

    fuzzy_prep<<<NC, ND, 0, stream>>>(centers, widths, W, packed);
    fuzzy_main<<<NB / 256, 256, 0, stream>>>(x, packed, out);
}